// Round 6
// baseline (1133.491 us; speedup 1.0000x reference)
//
#include <hip/hip_runtime.h>
#include <stdint.h>

// SpikingLinearLayer: spikes = LIF_scan(x @ W^T)  -- exact i8-limb MFMA path.
//   x: [20, 1024, 2048] fp32 binary; W: [2048, 2048] fp32; out fp32 binary.
//
// R9 -> R10: DELETE the barriers. Pure register-streaming GEMM.
//  * R4..R9 post-mortem: every barrier-locked variant lands 490-545us at
//    26-29% MfmaUtil. The invariant cost is the __syncthreads() vmcnt(0)
//    drain of same-region DMAs (issue->drain < 1 region) that 2 lockstep
//    waves/SIMD can't hide. Counted-vmcnt escapes raced (R7).
//  * R10: no LDS staging, no __syncthreads anywhere. Each wave streams its
//    own A (8x v4i) and B (4x v4i) from L2 into VGPRs and issues 32 MFMAs
//    per k-step. No inter-wave communication -> race-free by construction.
//    A's 4x inter-wave redundancy is L1/L2-absorbed (8KB chunk, re-read
//    back-to-back). Two waves/SIMD ping-pong freely (no lockstep).
//  * acc = 128 AGPR (TT=2) forces LIF V/I (64 VGPR fp64) into LDS --
//    R6-proven per-tid-private [e][tid] double2 layout, conflict-free b128,
//    no sync needed. Arch VGPR ~100 -> combined < 256 -> 2 waves/SIMD.
//  * prep_x rewritten coalesced: lane-contiguous float4 loads (was 64B-
//    strided per lane = 4x transaction inflation; preps are ~225us of total).
//  * Math byte-identical: same i8-limb planes, same fragment mapping, same
//    exact fp64 recombination + LIF.

constexpr int T_STEPS = 20;
constexpr int BATCH   = 1024;
constexpr int NIN     = 2048;
constexpr int NOUT    = 2048;

constexpr int    Q         = 4;
constexpr double SCALE     = 1073741824.0;     // 2^30
constexpr double INV_SCALE = 1.0 / SCALE;

constexpr size_t XI8_BYTES   = (size_t)T_STEPS * BATCH * NIN;        // 40 MB
constexpr size_t PLANE_BYTES = (size_t)NOUT * NIN;                   // 4 MB
constexpr size_t WS_NEEDED   = XI8_BYTES + (size_t)Q * PLANE_BYTES;  // 56 MB

typedef int v4i __attribute__((ext_vector_type(4)));

// ---------------------------------------------------------------- prep: x -> i8
// Coalesced: lane i handles float4 index (wave_base + q*64 + i) -> every load
// is 64 lanes x 16B contiguous; every store 64 lanes x 4B contiguous.
__global__ void prep_x(const float* __restrict__ x, int8_t* __restrict__ xi) {
    const int lane = threadIdx.x & 63;
    const int gw   = (blockIdx.x * blockDim.x + threadIdx.x) >> 6;  // global wave
    const size_t base = (size_t)gw * 256;                           // float4 idx
    const float4* xf = reinterpret_cast<const float4*>(x);
    char4* xc = reinterpret_cast<char4*>(xi);
#pragma unroll
    for (int q = 0; q < 4; ++q) {
        const size_t i = base + (size_t)q * 64 + lane;
        const float4 v = xf[i];
        xc[i] = make_char4((char)(v.x != 0.0f), (char)(v.y != 0.0f),
                           (char)(v.z != 0.0f), (char)(v.w != 0.0f));
    }
}

// ------------------------------------------------- prep: W -> 4 base-256 digits
__global__ void prep_limbs(const float* __restrict__ w, int8_t* __restrict__ limbs) {
    const int idx = blockIdx.x * blockDim.x + threadIdx.x;   // 4 weights each
    const float4 wv = reinterpret_cast<const float4*>(w)[idx];
    const float wf[4] = {wv.x, wv.y, wv.z, wv.w};
    int8_t d[Q][4];
#pragma unroll
    for (int e = 0; e < 4; ++e) {
        long long M = llrint((double)wf[e] * SCALE);         // |M| < 2^30
#pragma unroll
        for (int j = 0; j < Q - 1; ++j) {
            const int dj = (int)((M + 128) & 255) - 128;
            d[j][e] = (int8_t)dj;
            M = (M - dj) >> 8;                               // exact
        }
        d[Q - 1][e] = (int8_t)M;                             // |top| <= 65
    }
#pragma unroll
    for (int j = 0; j < Q; ++j)
        reinterpret_cast<char4*>(limbs + (size_t)j * PLANE_BYTES)[idx] =
            make_char4(d[j][0], d[j][1], d[j][2], d[j][3]);
}

// --------------------------------------------------------------- hot: i8 GEMMs
constexpr int KC     = 64;
constexpr int NKC    = NIN / KC;            // 32
constexpr int NTB    = T_STEPS / 2;         // 10 t-pairs

__global__ __launch_bounds__(256, 2)
void snn_i8(const int8_t* __restrict__ xi, const int8_t* __restrict__ limbs,
            float* __restrict__ out)
{
    // XCD swizzle: 4 o-tiles pinned per XCD -> limb set 4*512KB = 2MB in 4MB L2
    const int bid   = blockIdx.x;            // 512 blocks
    const int xcd   = bid & 7;
    const int sub   = bid >> 3;
    const int otile = xcd * 4 + (sub & 3);
    const int btile = sub >> 2;
    const int o0 = otile * 64, b0 = btile * 64;

    const int tid = threadIdx.x;
    const int w   = tid >> 6;     // wave id = o j-group owner
    const int ln  = tid & 63;
    const int lm  = ln & 15;
    const int qd  = ln >> 4;

    // LIF state in LDS, per-tid private (R6-proven layout, conflict-free b128).
    // No __syncthreads needed anywhere: slots are thread-private.
    __shared__ __align__(16) double2 ldsVI[16][256];   // 64 KB -> 2 blocks/CU

#pragma unroll
    for (int e = 0; e < 16; ++e)
        ldsVI[e][tid] = make_double2(0.0, 0.0);

    // per-lane fragment bases (identical mapping to R4/R5: lane ln holds
    // row lm of the 16-row group, k-bytes [qd*16, qd*16+16))
    const size_t a_lane = (size_t)(b0 + lm) * NIN + qd * 16;
    const size_t b_lane = (size_t)(o0 + 16 * w + lm) * NIN + qd * 16;
    const int8_t* bbase = limbs + b_lane;

    const double alpha_m = 1.0 - 1.0 / 20.0;
    const double alpha_s = 1.0 - 1.0 / 5.0;
    const double dtm     = 1.0 / 20.0;

    for (int tb = 0; tb < NTB; ++tb) {
        v4i acc0[4][4], acc1[4][4];   // [mg][plane]
#pragma unroll
        for (int mg = 0; mg < 4; ++mg)
#pragma unroll
            for (int j = 0; j < Q; ++j) {
                acc0[mg][j] = (v4i){0, 0, 0, 0};
                acc1[mg][j] = (v4i){0, 0, 0, 0};
            }

        const int8_t* xa = xi + (size_t)(2 * tb) * BATCH * NIN + a_lane;

        for (int kci = 0; kci < NKC; ++kci) {
            const int kc = kci << 6;

            // B fragments (wave-private o-group, t-invariant) from L2
            v4i B[4];
#pragma unroll
            for (int j = 0; j < Q; ++j)
                B[j] = *reinterpret_cast<const v4i*>(
                    bbase + (size_t)j * PLANE_BYTES + kc);

            // A fragments for all 4 row-groups x 2 timesteps from L2
            v4i A0[4], A1[4];
#pragma unroll
            for (int mg = 0; mg < 4; ++mg) {
                A0[mg] = *reinterpret_cast<const v4i*>(
                    xa + (size_t)(16 * mg) * NIN + kc);
                A1[mg] = *reinterpret_cast<const v4i*>(
                    xa + (size_t)BATCH * NIN + (size_t)(16 * mg) * NIN + kc);
            }

#pragma unroll
            for (int mg = 0; mg < 4; ++mg)
#pragma unroll
                for (int j = 0; j < Q; ++j) {
                    acc0[mg][j] = __builtin_amdgcn_mfma_i32_16x16x64_i8(
                        A0[mg], B[j], acc0[mg][j], 0, 0, 0);
                    acc1[mg][j] = __builtin_amdgcn_mfma_i32_16x16x64_i8(
                        A1[mg], B[j], acc1[mg][j], 0, 0, 0);
                }
        }

        // recombine digits (exact fp64), LIF (state in LDS), emit t-pair
        const int ocol = o0 + 16 * w + lm;
#pragma unroll
        for (int mg = 0; mg < 4; ++mg) {
#pragma unroll
            for (int r = 0; r < 4; ++r) {
                const int e = mg * 4 + r;
                const double2 vi = ldsVI[e][tid];
                double Vv = vi.x, Iv = vi.y;
                const int brow = b0 + 16 * mg + 4 * qd + r;
#pragma unroll
                for (int tt = 0; tt < 2; ++tt) {
                    const int d0 = tt ? acc1[mg][0][r] : acc0[mg][0][r];
                    const int d1 = tt ? acc1[mg][1][r] : acc0[mg][1][r];
                    const int d2 = tt ? acc1[mg][2][r] : acc0[mg][2][r];
                    const int d3 = tt ? acc1[mg][3][r] : acc0[mg][3][r];
                    double sm = (double)d3;
                    sm = sm * 256.0 + (double)d2;
                    sm = sm * 256.0 + (double)d1;
                    sm = sm * 256.0 + (double)d0;
                    const double cur = sm * INV_SCALE;

                    Iv = alpha_s * Iv + cur;
                    Vv = alpha_m * Vv + dtm * Iv;
                    const double sp = (Vv >= 1.0) ? 1.0 : 0.0;
                    Vv *= (1.0 - sp);

                    out[(size_t)(2 * tb + tt) * BATCH * NOUT
                        + (size_t)brow * NOUT + ocol] = (float)sp;
                }
                ldsVI[e][tid] = make_double2(Vv, Iv);
            }
        }
    }
}

// ------------------------------------------------ fallback: verified R1 kernel
constexpr int TBF = 64, TOF = 64, KCF = 64, LDPF = KCF + 4;

__global__ __launch_bounds__(256, 2)
void snn_fused(const float* __restrict__ x,
               const float* __restrict__ w,
               float* __restrict__ out)
{
    const int o0  = blockIdx.x * TOF;
    const int b0  = blockIdx.y * TBF;
    const int tid = threadIdx.x;
    const int tx  = tid & 15;
    const int ty  = tid >> 4;

    __shared__ float xs[TBF][LDPF];
    __shared__ float ws[TOF][LDPF];

    const int lr = tid >> 2;
    const int lc = (tid & 3) << 4;

    double V[4][4], I[4][4];
#pragma unroll
    for (int i = 0; i < 4; ++i)
#pragma unroll
        for (int j = 0; j < 4; ++j) { V[i][j] = 0.0; I[i][j] = 0.0; }

    const double alpha_m = 1.0 - 1.0 / 20.0;
    const double alpha_s = 1.0 - 1.0 / 5.0;
    const double dtm     = 1.0 / 20.0;

    for (int t = 0; t < T_STEPS; ++t) {
        const float* xt = x + (size_t)t * BATCH * NIN;
        double c[4][4];
#pragma unroll
        for (int i = 0; i < 4; ++i)
#pragma unroll
            for (int j = 0; j < 4; ++j) c[i][j] = 0.0;

        for (int kc = 0; kc < NIN; kc += KCF) {
            __syncthreads();
            {
                const float4* xg = reinterpret_cast<const float4*>(
                    xt + (size_t)(b0 + lr) * NIN + kc + lc);
                const float4* wg = reinterpret_cast<const float4*>(
                    w + (size_t)(o0 + lr) * NIN + kc + lc);
#pragma unroll
                for (int q = 0; q < 4; ++q) {
                    float4 xv = xg[q];
                    float4 wv4 = wg[q];
                    const int cbi = lc + q * 4;
                    xs[lr][cbi + 0] = xv.x;  xs[lr][cbi + 1] = xv.y;
                    xs[lr][cbi + 2] = xv.z;  xs[lr][cbi + 3] = xv.w;
                    ws[lr][cbi + 0] = wv4.x; ws[lr][cbi + 1] = wv4.y;
                    ws[lr][cbi + 2] = wv4.z; ws[lr][cbi + 3] = wv4.w;
                }
            }
            __syncthreads();

#pragma unroll 8
            for (int k = 0; k < KCF; ++k) {
                float xa[4], wa[4];
#pragma unroll
                for (int i = 0; i < 4; ++i) xa[i] = xs[ty * 4 + i][k];
#pragma unroll
                for (int j = 0; j < 4; ++j) wa[j] = ws[tx * 4 + j][k];
#pragma unroll
                for (int i = 0; i < 4; ++i)
#pragma unroll
                    for (int j = 0; j < 4; ++j)
                        c[i][j] += (double)xa[i] * (double)wa[j];
            }
        }

#pragma unroll
        for (int i = 0; i < 4; ++i) {
            float sv[4];
#pragma unroll
            for (int j = 0; j < 4; ++j) {
                I[i][j] = alpha_s * I[i][j] + c[i][j];
                V[i][j] = alpha_m * V[i][j] + dtm * I[i][j];
                const double sp = (V[i][j] >= 1.0) ? 1.0 : 0.0;
                V[i][j] *= (1.0 - sp);
                sv[j] = (float)sp;
            }
            const size_t oidx = (size_t)t * BATCH * NOUT
                              + (size_t)(b0 + ty * 4 + i) * NOUT
                              + (size_t)(o0 + tx * 4);
            *reinterpret_cast<float4*>(out + oidx) =
                make_float4(sv[0], sv[1], sv[2], sv[3]);
        }
    }
}

extern "C" void kernel_launch(void* const* d_in, const int* in_sizes, int n_in,
                              void* d_out, int out_size, void* d_ws, size_t ws_size,
                              hipStream_t stream) {
    const float* x = (const float*)d_in[0];
    const float* w = (const float*)d_in[1];
    float* out     = (float*)d_out;
    (void)in_sizes; (void)n_in; (void)out_size;

    if (ws_size >= WS_NEEDED) {
        int8_t* xi    = (int8_t*)d_ws;
        int8_t* limbs = xi + XI8_BYTES;
        prep_x<<<(int)(XI8_BYTES / 16 / 256), 256, 0, stream>>>(x, xi);
        prep_limbs<<<(int)(PLANE_BYTES / 4 / 256), 256, 0, stream>>>(w, limbs);
        snn_i8<<<512, 256, 0, stream>>>(xi, limbs, out);
    } else {
        dim3 grid(NOUT / TOF, BATCH / TBF);
        snn_fused<<<grid, dim3(256), 0, stream>>>(x, w, out);
    }
}

// Round 7
// 679.945 us; speedup vs baseline: 1.6670x; 1.6670x over previous
//
#include <hip/hip_runtime.h>
#include <stdint.h>

// SpikingLinearLayer: spikes = LIF_scan(x @ W^T)  -- exact i8-limb MFMA path.
//   x: [20, 1024, 2048] fp32 binary; W: [2048, 2048] fp32; out fp32 binary.
//
// R10 -> R11: cut per-CU fetched bytes; keep R4's replay-proven sync exactly.
//  * Model (fits R4/R8/R9/R10 within 10%): runtime = per-CU fetched bytes /
//    ~13 B/cyc/CU. The kernel is CU-side fetch-BW bound, not sync- or
//    latency-bound. MfmaUtil 29% is the consequence (1306 cyc MFMA under a
//    2460 cyc fetch shadow per region).
//  * Minimize bytes: A_total = 40MB x (2048/OB); B_total = 16MB x (1024/MB)
//    x (20/TT); constraint MB*OB*TT <= 16384 (128 AGPR acc/wave).
//    R4 (64x64,TT2, 2blk/CU): 3.93 GB. R11 (128x64, TT2, 512thr, 8 waves,
//    grid 256 = 1 block/CU): 2.62 GB = 10.24 MB/CU -> predicted ~330-380us.
//  * Same per-region sync as R4: all staging via global_load_lds, ONE
//    __syncthreads() per region, no inline asm. Fragment mapping, limb math,
//    fp64 LIF byte-identical.
//  * 8 waves: wave w -> (wm=w>>2: batch half, wn=w&3: o-group). Staging:
//    wave w deposits A(th=w&1, rg=(w>>1)*2+{0,1}) and B(j=w>>1,
//    og=(w&1)*2+{0,1}) = 4 dma16/wave = 32KB/block/region.

constexpr int T_STEPS = 20;
constexpr int BATCH   = 1024;
constexpr int NIN     = 2048;
constexpr int NOUT    = 2048;

constexpr int    Q         = 4;
constexpr double SCALE     = 1073741824.0;     // 2^30
constexpr double INV_SCALE = 1.0 / SCALE;

constexpr size_t XI8_BYTES   = (size_t)T_STEPS * BATCH * NIN;        // 40 MB
constexpr size_t PLANE_BYTES = (size_t)NOUT * NIN;                   // 4 MB
constexpr size_t WS_NEEDED   = XI8_BYTES + (size_t)Q * PLANE_BYTES;  // 56 MB

typedef int v4i __attribute__((ext_vector_type(4)));

// async 16B/lane global->LDS DMA: lds dst = uniform base + lane*16
__device__ __forceinline__ void dma16(const int8_t* g, const int8_t* l) {
    __builtin_amdgcn_global_load_lds(
        (const __attribute__((address_space(1))) void*)(uintptr_t)g,
        (__attribute__((address_space(3))) void*)(uint32_t)(uintptr_t)l,
        16, 0, 0);
}

// ---------------------------------------------------------------- prep: x -> i8
// Coalesced: lane i handles float4 index (wave_base + q*64 + i).
__global__ void prep_x(const float* __restrict__ x, int8_t* __restrict__ xi) {
    const int lane = threadIdx.x & 63;
    const int gw   = (blockIdx.x * blockDim.x + threadIdx.x) >> 6;  // global wave
    const size_t base = (size_t)gw * 256;                           // float4 idx
    const float4* xf = reinterpret_cast<const float4*>(x);
    char4* xc = reinterpret_cast<char4*>(xi);
#pragma unroll
    for (int q = 0; q < 4; ++q) {
        const size_t i = base + (size_t)q * 64 + lane;
        const float4 v = xf[i];
        xc[i] = make_char4((char)(v.x != 0.0f), (char)(v.y != 0.0f),
                           (char)(v.z != 0.0f), (char)(v.w != 0.0f));
    }
}

// ------------------------------------------------- prep: W -> 4 base-256 digits
__global__ void prep_limbs(const float* __restrict__ w, int8_t* __restrict__ limbs) {
    const int idx = blockIdx.x * blockDim.x + threadIdx.x;   // 4 weights each
    const float4 wv = reinterpret_cast<const float4*>(w)[idx];
    const float wf[4] = {wv.x, wv.y, wv.z, wv.w};
    int8_t d[Q][4];
#pragma unroll
    for (int e = 0; e < 4; ++e) {
        long long M = llrint((double)wf[e] * SCALE);         // |M| < 2^30
#pragma unroll
        for (int j = 0; j < Q - 1; ++j) {
            const int dj = (int)((M + 128) & 255) - 128;
            d[j][e] = (int8_t)dj;
            M = (M - dj) >> 8;                               // exact
        }
        d[Q - 1][e] = (int8_t)M;                             // |top| <= 65
    }
#pragma unroll
    for (int j = 0; j < Q; ++j)
        reinterpret_cast<char4*>(limbs + (size_t)j * PLANE_BYTES)[idx] =
            make_char4(d[j][0], d[j][1], d[j][2], d[j][3]);
}

// --------------------------------------------------------------- hot: i8 GEMMs
constexpr int KC     = 64;
constexpr int NKC    = NIN / KC;            // 32
constexpr int NTB    = T_STEPS / 2;         // 10 t-pairs
constexpr int NITER  = NTB * NKC;           // 320
constexpr int BM     = 128;                 // batch tile (8 row-groups of 16)
constexpr int BO     = 64;                  // out tile   (4 o-groups of 16)
constexpr int B_OFF  = 16384;               // A: [th*8192+rg*1024]; B after
constexpr int ABUF   = 32768;               // 16KB A + 16KB B per buffer

__global__ __launch_bounds__(512, 2)
void snn_i8(const int8_t* __restrict__ xi, const int8_t* __restrict__ limbs,
            float* __restrict__ out)
{
    // XCD swizzle: 4 o-tiles pinned per XCD -> limb set 4*512KB = 2MB in 4MB L2
    const int bid   = blockIdx.x;            // 256 blocks = exactly 1 per CU
    const int xcd   = bid & 7;
    const int sub   = bid >> 3;              // 0..31
    const int otile = xcd * 4 + (sub & 3);   // 0..31
    const int btile = sub >> 2;              // 0..7
    const int o0 = otile * BO, b0 = btile * BM;

    const int tid = threadIdx.x;
    const int w   = tid >> 6;                // wave 0..7
    const int ln  = tid & 63;
    const int lm  = ln & 15;
    const int qd  = ln >> 4;
    const int wm  = w >> 2;                  // batch half (64 rows)
    const int wn  = w & 3;                   // o-group (16 cols)

    __shared__ __align__(16) int8_t lds[2][ABUF];   // 64 KB -> 1 block/CU

    // staging assignment for wave w (4 dma16 = 4 KB/wave/region):
    const int sa_th  = w & 1;                // A t-half
    const int sa_rg  = (w >> 1) * 2;         // A row-groups sa_rg, sa_rg+1
    const int sb_j   = w >> 1;               // B limb plane
    const int sb_og  = (w & 1) * 2;          // B o-groups sb_og, sb_og+1

    // per-lane global source offsets (row part; t/kc added in stage)
    const size_t a_src0 = (size_t)(b0 + 16 * sa_rg       + lm) * NIN + qd * 16;
    const size_t a_src1 = (size_t)(b0 + 16 * (sa_rg + 1) + lm) * NIN + qd * 16;
    const size_t b_src0 = (size_t)sb_j * PLANE_BYTES
                        + (size_t)(o0 + 16 * sb_og       + lm) * NIN + qd * 16;
    const size_t b_src1 = (size_t)sb_j * PLANE_BYTES
                        + (size_t)(o0 + 16 * (sb_og + 1) + lm) * NIN + qd * 16;

    // LIF state: e = mg*4+r -> b = b0+64wm+16mg+4qd+r, o = o0+16wn+lm
    double V[16], I[16];
#pragma unroll
    for (int e = 0; e < 16; ++e) { V[e] = 0.0; I[e] = 0.0; }

    const double alpha_m = 1.0 - 1.0 / 20.0;
    const double alpha_s = 1.0 - 1.0 / 5.0;
    const double dtm     = 1.0 / 20.0;

    // stage region s into lds[s&1]
    auto stage = [&](int s) {
        const int tb = s >> 5;
        const int kc = (s & 31) << 6;
        int8_t* lb = &lds[s & 1][0];
        const int8_t* xs = xi + (size_t)(2 * tb + sa_th) * BATCH * NIN + kc;
        dma16(xs + a_src0, lb + sa_th * 8192 + sa_rg * 1024);
        dma16(xs + a_src1, lb + sa_th * 8192 + (sa_rg + 1) * 1024);
        dma16(limbs + b_src0 + kc, lb + B_OFF + sb_j * 4096 + sb_og * 1024);
        dma16(limbs + b_src1 + kc, lb + B_OFF + sb_j * 4096 + (sb_og + 1) * 1024);
    };

    stage(0);
    __syncthreads();

    int s = 0;
    for (int tb = 0; tb < NTB; ++tb) {
        v4i acc0[4][4], acc1[4][4];   // [mg][plane]
#pragma unroll
        for (int mg = 0; mg < 4; ++mg)
#pragma unroll
            for (int j = 0; j < Q; ++j) {
                acc0[mg][j] = (v4i){0, 0, 0, 0};
                acc1[mg][j] = (v4i){0, 0, 0, 0};
            }

        for (int kci = 0; kci < NKC; ++kci, ++s) {
            if (s + 1 < NITER) stage(s + 1);            // async prefetch

            const int8_t* cb = &lds[s & 1][0];
            v4i B[4];
#pragma unroll
            for (int j = 0; j < Q; ++j)
                B[j] = *reinterpret_cast<const v4i*>(
                    cb + B_OFF + j * 4096 + wn * 1024 + ln * 16);
#pragma unroll
            for (int mg = 0; mg < 4; ++mg) {
                const int rg = 4 * wm + mg;
                const v4i A0 = *reinterpret_cast<const v4i*>(
                    cb + 0    + rg * 1024 + ln * 16);
                const v4i A1 = *reinterpret_cast<const v4i*>(
                    cb + 8192 + rg * 1024 + ln * 16);
#pragma unroll
                for (int j = 0; j < Q; ++j) {
                    acc0[mg][j] = __builtin_amdgcn_mfma_i32_16x16x64_i8(
                        A0, B[j], acc0[mg][j], 0, 0, 0);
                    acc1[mg][j] = __builtin_amdgcn_mfma_i32_16x16x64_i8(
                        A1, B[j], acc1[mg][j], 0, 0, 0);
                }
            }
            __syncthreads();   // drains DMA (already landed under the MFMAs)
        }

        // recombine digits (exact fp64), LIF, emit spikes for t-pair
        const int ocol = o0 + 16 * wn + lm;
#pragma unroll
        for (int tt = 0; tt < 2; ++tt) {
            const int t = 2 * tb + tt;
#pragma unroll
            for (int mg = 0; mg < 4; ++mg) {
#pragma unroll
                for (int r = 0; r < 4; ++r) {
                    const int d0 = tt ? acc1[mg][0][r] : acc0[mg][0][r];
                    const int d1 = tt ? acc1[mg][1][r] : acc0[mg][1][r];
                    const int d2 = tt ? acc1[mg][2][r] : acc0[mg][2][r];
                    const int d3 = tt ? acc1[mg][3][r] : acc0[mg][3][r];
                    double sm = (double)d3;
                    sm = sm * 256.0 + (double)d2;
                    sm = sm * 256.0 + (double)d1;
                    sm = sm * 256.0 + (double)d0;
                    const double cur = sm * INV_SCALE;

                    const int e = mg * 4 + r;
                    I[e] = alpha_s * I[e] + cur;
                    V[e] = alpha_m * V[e] + dtm * I[e];
                    const double sp = (V[e] >= 1.0) ? 1.0 : 0.0;
                    V[e] *= (1.0 - sp);

                    const int brow = b0 + 64 * wm + 16 * mg + 4 * qd + r;
                    __builtin_nontemporal_store(
                        (float)sp,
                        out + (size_t)t * BATCH * NOUT
                            + (size_t)brow * NOUT + ocol);
                }
            }
        }
    }
}

// ------------------------------------------------ fallback: verified R1 kernel
constexpr int TBF = 64, TOF = 64, KCF = 64, LDPF = KCF + 4;

__global__ __launch_bounds__(256, 2)
void snn_fused(const float* __restrict__ x,
               const float* __restrict__ w,
               float* __restrict__ out)
{
    const int o0  = blockIdx.x * TOF;
    const int b0  = blockIdx.y * TBF;
    const int tid = threadIdx.x;
    const int tx  = tid & 15;
    const int ty  = tid >> 4;

    __shared__ float xs[TBF][LDPF];
    __shared__ float ws[TOF][LDPF];

    const int lr = tid >> 2;
    const int lc = (tid & 3) << 4;

    double V[4][4], I[4][4];
#pragma unroll
    for (int i = 0; i < 4; ++i)
#pragma unroll
        for (int j = 0; j < 4; ++j) { V[i][j] = 0.0; I[i][j] = 0.0; }

    const double alpha_m = 1.0 - 1.0 / 20.0;
    const double alpha_s = 1.0 - 1.0 / 5.0;
    const double dtm     = 1.0 / 20.0;

    for (int t = 0; t < T_STEPS; ++t) {
        const float* xt = x + (size_t)t * BATCH * NIN;
        double c[4][4];
#pragma unroll
        for (int i = 0; i < 4; ++i)
#pragma unroll
            for (int j = 0; j < 4; ++j) c[i][j] = 0.0;

        for (int kc = 0; kc < NIN; kc += KCF) {
            __syncthreads();
            {
                const float4* xg = reinterpret_cast<const float4*>(
                    xt + (size_t)(b0 + lr) * NIN + kc + lc);
                const float4* wg = reinterpret_cast<const float4*>(
                    w + (size_t)(o0 + lr) * NIN + kc + lc);
#pragma unroll
                for (int q = 0; q < 4; ++q) {
                    float4 xv = xg[q];
                    float4 wv4 = wg[q];
                    const int cbi = lc + q * 4;
                    xs[lr][cbi + 0] = xv.x;  xs[lr][cbi + 1] = xv.y;
                    xs[lr][cbi + 2] = xv.z;  xs[lr][cbi + 3] = xv.w;
                    ws[lr][cbi + 0] = wv4.x; ws[lr][cbi + 1] = wv4.y;
                    ws[lr][cbi + 2] = wv4.z; ws[lr][cbi + 3] = wv4.w;
                }
            }
            __syncthreads();

#pragma unroll 8
            for (int k = 0; k < KCF; ++k) {
                float xa[4], wa[4];
#pragma unroll
                for (int i = 0; i < 4; ++i) xa[i] = xs[ty * 4 + i][k];
#pragma unroll
                for (int j = 0; j < 4; ++j) wa[j] = ws[tx * 4 + j][k];
#pragma unroll
                for (int i = 0; i < 4; ++i)
#pragma unroll
                    for (int j = 0; j < 4; ++j)
                        c[i][j] += (double)xa[i] * (double)wa[j];
            }
        }

#pragma unroll
        for (int i = 0; i < 4; ++i) {
            float sv[4];
#pragma unroll
            for (int j = 0; j < 4; ++j) {
                I[i][j] = alpha_s * I[i][j] + c[i][j];
                V[i][j] = alpha_m * V[i][j] + dtm * I[i][j];
                const double sp = (V[i][j] >= 1.0) ? 1.0 : 0.0;
                V[i][j] *= (1.0 - sp);
                sv[j] = (float)sp;
            }
            const size_t oidx = (size_t)t * BATCH * NOUT
                              + (size_t)(b0 + ty * 4 + i) * NOUT
                              + (size_t)(o0 + tx * 4);
            *reinterpret_cast<float4*>(out + oidx) =
                make_float4(sv[0], sv[1], sv[2], sv[3]);
        }
    }
}

extern "C" void kernel_launch(void* const* d_in, const int* in_sizes, int n_in,
                              void* d_out, int out_size, void* d_ws, size_t ws_size,
                              hipStream_t stream) {
    const float* x = (const float*)d_in[0];
    const float* w = (const float*)d_in[1];
    float* out     = (float*)d_out;
    (void)in_sizes; (void)n_in; (void)out_size;

    if (ws_size >= WS_NEEDED) {
        int8_t* xi    = (int8_t*)d_ws;
        int8_t* limbs = xi + XI8_BYTES;
        prep_x<<<(int)(XI8_BYTES / 16 / 256), 256, 0, stream>>>(x, xi);
        prep_limbs<<<(int)(PLANE_BYTES / 4 / 256), 256, 0, stream>>>(w, limbs);
        snn_i8<<<256, 512, 0, stream>>>(xi, limbs, out);
    } else {
        dim3 grid(NOUT / TOF, BATCH / TBF);
        snn_fused<<<grid, dim3(256), 0, stream>>>(x, w, out);
    }
}

// Round 8
// 556.247 us; speedup vs baseline: 2.0377x; 1.2224x over previous
//
#include <hip/hip_runtime.h>
#include <stdint.h>

// SpikingLinearLayer: spikes = LIF_scan(x @ W^T)  -- exact i8-limb MFMA path.
//   x: [20, 1024, 2048] fp32 binary; W: [2048, 2048] fp32; out fp32 binary.
//
// R11 -> R12: A is BINARY -- pack it to 1 bit/elem (8x), retile around it.
//  * Model (R4..R11): region = max(staged_bytes/13Bcyc, MFMA_issue) + ~800
//    barrier slop. R11 sat at the byte-optimum for 1B/elem A. Packing A to
//    bits (5 MB total, L2/L3-resident) makes A traffic ~free -> AM-GM moves
//    to BM=256, OB=16, TT=4: chip traffic 2.62 GB -> 0.98 GB, and the
//    region flips to MFMA-BOUND (fetch 1846 cyc < issue 2611 cyc/SIMD).
//  * In-register expansion: ds_read_u16 (16 k-bits) -> 4 dwords via
//    ((b>>4q)&0xF)*0x00204081 & 0x01010101 (12 VALU/frag, idle VALU pipe,
//    m114 overlap). MFMA inputs stay exactly {0,1} -> bit-identical accs.
//  * KC=128/region, NITER=80 (4x fewer barriers than R11). Sync is the
//    replay-proven R4 pattern: all staging via global_load_lds, ONE
//    __syncthreads()/region, no inline asm, no setprio.
//  * acc = rg2(2) x tt(4) x limb(4) = 32 v4i = 128 AGPR (unchanged budget).
//  * prep_x -> __ballot bit-packer (writes 5 MB, not 40). ws need: 21 MB.

constexpr int T_STEPS = 20;
constexpr int BATCH   = 1024;
constexpr int NIN     = 2048;
constexpr int NOUT    = 2048;

constexpr int    Q         = 4;
constexpr double SCALE     = 1073741824.0;     // 2^30
constexpr double INV_SCALE = 1.0 / SCALE;

// packed x: [t][kc2(16)][b(1024)][16B]  (16B = 128 k-bits)
constexpr size_t XIP_BYTES   = (size_t)T_STEPS * 16 * 1024 * 16;     // 5 MB
constexpr size_t PLANE_BYTES = (size_t)NOUT * NIN;                   // 4 MB
constexpr size_t WS_NEEDED   = XIP_BYTES + (size_t)Q * PLANE_BYTES;  // 21 MB

typedef int v4i __attribute__((ext_vector_type(4)));

// async 16B/lane global->LDS DMA: lds dst = uniform base + lane*16
__device__ __forceinline__ void dma16(const int8_t* g, const int8_t* l) {
    __builtin_amdgcn_global_load_lds(
        (const __attribute__((address_space(1))) void*)(uintptr_t)g,
        (__attribute__((address_space(3))) void*)(uint32_t)(uintptr_t)l,
        16, 0, 0);
}

// 16 bits -> 16 bytes {0,1} (4 dwords), little-endian k-ascending
__device__ __forceinline__ v4i expand16(uint32_t b) {
    v4i r;
    r[0] = (int)((((b      ) & 0xFu) * 0x00204081u) & 0x01010101u);
    r[1] = (int)((((b >>  4) & 0xFu) * 0x00204081u) & 0x01010101u);
    r[2] = (int)((((b >>  8) & 0xFu) * 0x00204081u) & 0x01010101u);
    r[3] = (int)((((b >> 12) & 0xFu) * 0x00204081u) & 0x01010101u);
    return r;
}

// ------------------------------------------- prep: x -> packed bits (ballot)
// one wave per (t,b) row; 32 ballots of 64 consecutive k each.
__global__ void prep_x(const float* __restrict__ x, int8_t* __restrict__ xp) {
    const int tid  = threadIdx.x;
    const int ln   = tid & 63;
    const int row  = blockIdx.x * 4 + (tid >> 6);        // 20480 rows
    const int t    = row >> 10;
    const int b    = row & 1023;
    const float* xr = x + (size_t)row * NIN;
#pragma unroll
    for (int c = 0; c < 32; ++c) {                       // k = c*64 + ln
        const unsigned long long m = __ballot(xr[c * 64 + ln] != 0.0f);
        if (ln == 0)
            *reinterpret_cast<unsigned long long*>(
                xp + (((size_t)t * 16 + (c >> 1)) * 1024 + b) * 16
                   + (c & 1) * 8) = m;
    }
}

// ------------------------------------------------- prep: W -> 4 base-256 digits
__global__ void prep_limbs(const float* __restrict__ w, int8_t* __restrict__ limbs) {
    const int idx = blockIdx.x * blockDim.x + threadIdx.x;   // 4 weights each
    const float4 wv = reinterpret_cast<const float4*>(w)[idx];
    const float wf[4] = {wv.x, wv.y, wv.z, wv.w};
    int8_t d[Q][4];
#pragma unroll
    for (int e = 0; e < 4; ++e) {
        long long M = llrint((double)wf[e] * SCALE);         // |M| < 2^30
#pragma unroll
        for (int j = 0; j < Q - 1; ++j) {
            const int dj = (int)((M + 128) & 255) - 128;
            d[j][e] = (int8_t)dj;
            M = (M - dj) >> 8;                               // exact
        }
        d[Q - 1][e] = (int8_t)M;                             // |top| <= 65
    }
#pragma unroll
    for (int j = 0; j < Q; ++j)
        reinterpret_cast<char4*>(limbs + (size_t)j * PLANE_BYTES)[idx] =
            make_char4(d[j][0], d[j][1], d[j][2], d[j][3]);
}

// --------------------------------------------------------------- hot: i8 GEMMs
constexpr int KC2    = 128;                 // K per region
constexpr int NKC2   = NIN / KC2;           // 16
constexpr int TT     = 4;                   // timesteps per sweep
constexpr int NTQ    = T_STEPS / TT;        // 5 t-quads
constexpr int NITER  = NTQ * NKC2;          // 80 regions
constexpr int BM     = 256;                 // batch tile (16 rg of 16)
constexpr int BO     = 16;                  // out tile (1 o-group)
constexpr int B_OFF  = 16384;               // A: 16KB packed-bits; B: 8KB i8
constexpr int BUF_B  = 24576;

__global__ __launch_bounds__(512, 2)
void snn_i8(const int8_t* __restrict__ xp, const int8_t* __restrict__ limbs,
            float* __restrict__ out)
{
    // XCD swizzle: 16 o-tiles per XCD -> B slice 2MB in L2; A-packed 5MB in L3
    const int bid   = blockIdx.x;            // 512 blocks
    const int xcd   = bid & 7;
    const int sub   = bid >> 3;              // 0..63
    const int otile = xcd * 16 + (sub & 15); // 0..127
    const int btile = sub >> 4;              // 0..3
    const int o0 = otile * BO, b0 = btile * BM;

    const int tid = threadIdx.x;
    const int w   = tid >> 6;                // wave 0..7: owns rows 32w..32w+31
    const int ln  = tid & 63;
    const int lm  = ln & 15;
    const int qd  = ln >> 4;

    __shared__ __align__(16) int8_t lds[2][BUF_B];   // 48 KB

    // staging assignment (3 dma16/wave/region):
    const int sa_tt = w >> 1;                // A t-step
    const int sa_g  = (w & 1) * 2;           // A row-chunks g, g+1 (64 rows ea)
    const int sb_j  = w >> 1;                // B limb plane
    const int sb_h  = w & 1;                 // B k-half

    // B source (per-lane): plane sb_j, row o0+lm, k-bytes h*64 + qd*16
    const size_t b_src = (size_t)sb_j * PLANE_BYTES
                       + (size_t)(o0 + lm) * NIN + sb_h * 64 + qd * 16;

    // LIF state: e = rg2*4+r -> b = b0+(2w+rg2)*16+4qd+r, o = o0+lm
    double V[8], I[8];
#pragma unroll
    for (int e = 0; e < 8; ++e) { V[e] = 0.0; I[e] = 0.0; }

    const double alpha_m = 1.0 - 1.0 / 20.0;
    const double alpha_s = 1.0 - 1.0 / 5.0;
    const double dtm     = 1.0 / 20.0;

    // stage region s into lds[s&1]: A 2 dma (128 rows x 16B bits), B 1 dma
    auto stage = [&](int s) {
        const int tq  = s >> 4;
        const int kc2 = s & 15;
        int8_t* lb = &lds[s & 1][0];
        const size_t abase =
            (((size_t)(tq * 4 + sa_tt) * 16 + kc2) * 1024 + b0) * 16;
        dma16(xp + abase + (size_t)(sa_g * 64 + ln) * 16,
              lb + (sa_tt * 4 + sa_g) * 1024);
        dma16(xp + abase + (size_t)((sa_g + 1) * 64 + ln) * 16,
              lb + (sa_tt * 4 + sa_g + 1) * 1024);
        dma16(limbs + b_src + (size_t)kc2 * KC2,
              lb + B_OFF + (sb_j * 2 + sb_h) * 1024);
    };

    stage(0);
    __syncthreads();

    int s = 0;
    for (int tq = 0; tq < NTQ; ++tq) {
        v4i acc[2][4][4];   // [rg2][tt][plane]
#pragma unroll
        for (int rg2 = 0; rg2 < 2; ++rg2)
#pragma unroll
            for (int tt = 0; tt < TT; ++tt)
#pragma unroll
                for (int j = 0; j < Q; ++j)
                    acc[rg2][tt][j] = (v4i){0, 0, 0, 0};

        for (int kci = 0; kci < NKC2; ++kci, ++s) {
            if (s + 1 < NITER) stage(s + 1);            // async prefetch

            const int8_t* cb = &lds[s & 1][0];
#pragma unroll
            for (int s2 = 0; s2 < 2; ++s2) {            // two K=64 sub-chunks
                v4i B[4];
#pragma unroll
                for (int j = 0; j < Q; ++j)
                    B[j] = *reinterpret_cast<const v4i*>(
                        cb + B_OFF + ((j * 2 + s2) * 64 + ln) * 16);
#pragma unroll
                for (int rg2 = 0; rg2 < 2; ++rg2) {
                    const int r = (2 * w + rg2) * 16 + lm;
#pragma unroll
                    for (int tt = 0; tt < TT; ++tt) {
                        const uint32_t bits =
                            *reinterpret_cast<const uint16_t*>(
                                cb + tt * 4096 + r * 16 + s2 * 8 + qd * 2);
                        const v4i A = expand16(bits);
#pragma unroll
                        for (int j = 0; j < Q; ++j)
                            acc[rg2][tt][j] =
                                __builtin_amdgcn_mfma_i32_16x16x64_i8(
                                    A, B[j], acc[rg2][tt][j], 0, 0, 0);
                    }
                }
            }
            __syncthreads();   // drains DMA (landed under 128 MFMAs)
        }

        // recombine digits (exact fp64), LIF, emit spikes for t-quad
        const int ocol = o0 + lm;
#pragma unroll
        for (int rg2 = 0; rg2 < 2; ++rg2) {
#pragma unroll
            for (int r = 0; r < 4; ++r) {
                const int e = rg2 * 4 + r;
                const int brow = b0 + (2 * w + rg2) * 16 + 4 * qd + r;
#pragma unroll
                for (int tt = 0; tt < TT; ++tt) {
                    const int d0 = acc[rg2][tt][0][r];
                    const int d1 = acc[rg2][tt][1][r];
                    const int d2 = acc[rg2][tt][2][r];
                    const int d3 = acc[rg2][tt][3][r];
                    double sm = (double)d3;
                    sm = sm * 256.0 + (double)d2;
                    sm = sm * 256.0 + (double)d1;
                    sm = sm * 256.0 + (double)d0;
                    const double cur = sm * INV_SCALE;

                    I[e] = alpha_s * I[e] + cur;
                    V[e] = alpha_m * V[e] + dtm * I[e];
                    const double sp = (V[e] >= 1.0) ? 1.0 : 0.0;
                    V[e] *= (1.0 - sp);

                    __builtin_nontemporal_store(
                        (float)sp,
                        out + (size_t)(tq * 4 + tt) * BATCH * NOUT
                            + (size_t)brow * NOUT + ocol);
                }
            }
        }
    }
}

// ------------------------------------------------ fallback: verified R1 kernel
constexpr int TBF = 64, TOF = 64, KCF = 64, LDPF = KCF + 4;

__global__ __launch_bounds__(256, 2)
void snn_fused(const float* __restrict__ x,
               const float* __restrict__ w,
               float* __restrict__ out)
{
    const int o0  = blockIdx.x * TOF;
    const int b0  = blockIdx.y * TBF;
    const int tid = threadIdx.x;
    const int tx  = tid & 15;
    const int ty  = tid >> 4;

    __shared__ float xs[TBF][LDPF];
    __shared__ float ws[TOF][LDPF];

    const int lr = tid >> 2;
    const int lc = (tid & 3) << 4;

    double V[4][4], I[4][4];
#pragma unroll
    for (int i = 0; i < 4; ++i)
#pragma unroll
        for (int j = 0; j < 4; ++j) { V[i][j] = 0.0; I[i][j] = 0.0; }

    const double alpha_m = 1.0 - 1.0 / 20.0;
    const double alpha_s = 1.0 - 1.0 / 5.0;
    const double dtm     = 1.0 / 20.0;

    for (int t = 0; t < T_STEPS; ++t) {
        const float* xt = x + (size_t)t * BATCH * NIN;
        double c[4][4];
#pragma unroll
        for (int i = 0; i < 4; ++i)
#pragma unroll
            for (int j = 0; j < 4; ++j) c[i][j] = 0.0;

        for (int kc = 0; kc < NIN; kc += KCF) {
            __syncthreads();
            {
                const float4* xg = reinterpret_cast<const float4*>(
                    xt + (size_t)(b0 + lr) * NIN + kc + lc);
                const float4* wg = reinterpret_cast<const float4*>(
                    w + (size_t)(o0 + lr) * NIN + kc + lc);
#pragma unroll
                for (int q = 0; q < 4; ++q) {
                    float4 xv = xg[q];
                    float4 wv4 = wg[q];
                    const int cbi = lc + q * 4;
                    xs[lr][cbi + 0] = xv.x;  xs[lr][cbi + 1] = xv.y;
                    xs[lr][cbi + 2] = xv.z;  xs[lr][cbi + 3] = xv.w;
                    ws[lr][cbi + 0] = wv4.x; ws[lr][cbi + 1] = wv4.y;
                    ws[lr][cbi + 2] = wv4.z; ws[lr][cbi + 3] = wv4.w;
                }
            }
            __syncthreads();

#pragma unroll 8
            for (int k = 0; k < KCF; ++k) {
                float xa[4], wa[4];
#pragma unroll
                for (int i = 0; i < 4; ++i) xa[i] = xs[ty * 4 + i][k];
#pragma unroll
                for (int j = 0; j < 4; ++j) wa[j] = ws[tx * 4 + j][k];
#pragma unroll
                for (int i = 0; i < 4; ++i)
#pragma unroll
                    for (int j = 0; j < 4; ++j)
                        c[i][j] += (double)xa[i] * (double)wa[j];
            }
        }

#pragma unroll
        for (int i = 0; i < 4; ++i) {
            float sv[4];
#pragma unroll
            for (int j = 0; j < 4; ++j) {
                I[i][j] = alpha_s * I[i][j] + c[i][j];
                V[i][j] = alpha_m * V[i][j] + dtm * I[i][j];
                const double sp = (V[i][j] >= 1.0) ? 1.0 : 0.0;
                V[i][j] *= (1.0 - sp);
                sv[j] = (float)sp;
            }
            const size_t oidx = (size_t)t * BATCH * NOUT
                              + (size_t)(b0 + ty * 4 + i) * NOUT
                              + (size_t)(o0 + tx * 4);
            *reinterpret_cast<float4*>(out + oidx) =
                make_float4(sv[0], sv[1], sv[2], sv[3]);
        }
    }
}

extern "C" void kernel_launch(void* const* d_in, const int* in_sizes, int n_in,
                              void* d_out, int out_size, void* d_ws, size_t ws_size,
                              hipStream_t stream) {
    const float* x = (const float*)d_in[0];
    const float* w = (const float*)d_in[1];
    float* out     = (float*)d_out;
    (void)in_sizes; (void)n_in; (void)out_size;

    if (ws_size >= WS_NEEDED) {
        int8_t* xp    = (int8_t*)d_ws;
        int8_t* limbs = xp + XIP_BYTES;
        prep_x<<<5120, 256, 0, stream>>>(x, xp);
        prep_limbs<<<(int)(PLANE_BYTES / 4 / 256), 256, 0, stream>>>(w, limbs);
        snn_i8<<<512, 512, 0, stream>>>(xp, limbs, out);
    } else {
        dim3 grid(NOUT / TOF, BATCH / TBF);
        snn_fused<<<grid, dim3(256), 0, stream>>>(x, w, out);
    }
}